// Round 1
// baseline (1548.359 us; speedup 1.0000x reference)
//
#include <hip/hip_runtime.h>
#include <cmath>

#define NROWS 4096   // B*S
#define DM    1024   // model dim

// ---------------- LayerNorm: one block (256 thr) per row of 1024 ----------------
__global__ __launch_bounds__(256) void ln_kernel(
    const float* __restrict__ x, const float* __restrict__ g,
    const float* __restrict__ beta, float* __restrict__ out)
{
    const int row = blockIdx.x;
    const int t = threadIdx.x;
    const float4 v = ((const float4*)(x + (size_t)row * DM))[t];
    float s = v.x + v.y + v.z + v.w;
    #pragma unroll
    for (int off = 32; off > 0; off >>= 1) s += __shfl_xor(s, off);
    __shared__ float red[4];
    const int wid = t >> 6;
    if ((t & 63) == 0) red[wid] = s;
    __syncthreads();
    const float mean = (red[0] + red[1] + red[2] + red[3]) * (1.0f / DM);
    const float dx = v.x - mean, dy = v.y - mean, dz = v.z - mean, dw = v.w - mean;
    float ss = dx*dx + dy*dy + dz*dz + dw*dw;
    #pragma unroll
    for (int off = 32; off > 0; off >>= 1) ss += __shfl_xor(ss, off);
    __syncthreads();
    if ((t & 63) == 0) red[wid] = ss;
    __syncthreads();
    const float var = (red[0] + red[1] + red[2] + red[3]) * (1.0f / DM);
    const float rstd = rsqrtf(var + 1e-5f);
    const float4 gv = ((const float4*)g)[t];
    const float4 bv = ((const float4*)beta)[t];
    float4 o;
    o.x = dx * rstd * gv.x + bv.x;
    o.y = dy * rstd * gv.y + bv.y;
    o.z = dz * rstd * gv.z + bv.z;
    o.w = dw * rstd * gv.w + bv.w;
    ((float4*)(out + (size_t)row * DM))[t] = o;
}

__device__ __forceinline__ float gelu_f(float v) {
    return 0.5f * v * (1.0f + erff(v * 0.70710678118654752f));
}

// ---------------- GEMM: C[M,N] = act(A[M,K] @ W[N,K]^T + bias) (+ res) ----------------
// 128x128 tile, BK=16, 8x8 microtile per thread, 256 threads.
__global__ __launch_bounds__(256, 2) void gemm_kernel(
    const float* __restrict__ A, const float* __restrict__ W,
    const float* __restrict__ bias, const float* __restrict__ res,
    float* __restrict__ C, int N, int K, int act)
{
    __shared__ __align__(16) float As[16][132];   // [k][m], +4 pad: conflict-free
    __shared__ __align__(16) float Ws[16][132];   // [k][n]
    const int tid = threadIdx.x;
    const int tx = tid & 15, ty = tid >> 4;
    const int m0 = blockIdx.y * 128, n0 = blockIdx.x * 128;
    const int c4 = tid & 3, rr = tid >> 2;        // loader: 4 k-floats x rows rr, rr+64

    const float* Ap0 = A + (size_t)(m0 + rr) * K + c4 * 4;
    const float* Ap1 = A + (size_t)(m0 + rr + 64) * K + c4 * 4;
    const float* Wp0 = W + (size_t)(n0 + rr) * K + c4 * 4;
    const float* Wp1 = W + (size_t)(n0 + rr + 64) * K + c4 * 4;

    float acc[8][8] = {};

    for (int kb = 0; kb < K; kb += 16) {
        const float4 a0 = *(const float4*)(Ap0 + kb);
        const float4 a1 = *(const float4*)(Ap1 + kb);
        const float4 w0 = *(const float4*)(Wp0 + kb);
        const float4 w1 = *(const float4*)(Wp1 + kb);
        __syncthreads();
        const int kc = c4 * 4;
        As[kc+0][rr] = a0.x; As[kc+1][rr] = a0.y; As[kc+2][rr] = a0.z; As[kc+3][rr] = a0.w;
        As[kc+0][rr+64] = a1.x; As[kc+1][rr+64] = a1.y; As[kc+2][rr+64] = a1.z; As[kc+3][rr+64] = a1.w;
        Ws[kc+0][rr] = w0.x; Ws[kc+1][rr] = w0.y; Ws[kc+2][rr] = w0.z; Ws[kc+3][rr] = w0.w;
        Ws[kc+0][rr+64] = w1.x; Ws[kc+1][rr+64] = w1.y; Ws[kc+2][rr+64] = w1.z; Ws[kc+3][rr+64] = w1.w;
        __syncthreads();
        #pragma unroll
        for (int kk = 0; kk < 16; kk++) {
            const float4 aLo = *(const float4*)&As[kk][ty * 8];
            const float4 aHi = *(const float4*)&As[kk][ty * 8 + 4];
            const float4 bLo = *(const float4*)&Ws[kk][tx * 8];
            const float4 bHi = *(const float4*)&Ws[kk][tx * 8 + 4];
            const float av[8] = {aLo.x, aLo.y, aLo.z, aLo.w, aHi.x, aHi.y, aHi.z, aHi.w};
            const float bv[8] = {bLo.x, bLo.y, bLo.z, bLo.w, bHi.x, bHi.y, bHi.z, bHi.w};
            #pragma unroll
            for (int i = 0; i < 8; i++)
                #pragma unroll
                for (int j = 0; j < 8; j++)
                    acc[i][j] += av[i] * bv[j];
        }
    }

    const int nbase = n0 + tx * 8;
    float bia[8];
    #pragma unroll
    for (int j = 0; j < 8; j++) bia[j] = bias[nbase + j];
    #pragma unroll
    for (int i = 0; i < 8; i++) {
        const size_t off = (size_t)(m0 + ty * 8 + i) * N + nbase;
        float vv[8];
        #pragma unroll
        for (int j = 0; j < 8; j++) {
            float v = acc[i][j] + bia[j];
            if (act) v = gelu_f(v);
            vv[j] = v;
        }
        if (res) {
            const float4 q0 = *(const float4*)(res + off);
            const float4 q1 = *(const float4*)(res + off + 4);
            vv[0]+=q0.x; vv[1]+=q0.y; vv[2]+=q0.z; vv[3]+=q0.w;
            vv[4]+=q1.x; vv[5]+=q1.y; vv[6]+=q1.z; vv[7]+=q1.w;
        }
        *(float4*)(C + off)     = make_float4(vv[0], vv[1], vv[2], vv[3]);
        *(float4*)(C + off + 4) = make_float4(vv[4], vv[5], vv[6], vv[7]);
    }
}

// ---------------- Flash attention, fp32, causal, softcap 6*tanh(s/6) ----------------
// qkv: [B*S, 3072] with cols = [q(h*64+d) | 1024 + h*64+d | 2048 + h*64+d]
// grid: (S/32 q-tiles, B*H); block 256 = 16tx x 16ty; thread: 2 rows x 4 cols.
__global__ __launch_bounds__(256, 2) void attn_kernel(
    const float* __restrict__ qkv, float* __restrict__ o)
{
    const int qt = blockIdx.x;   // 0..31
    const int bh = blockIdx.y;   // 0..63
    const int bb = bh >> 4, h = bh & 15;
    const float* base = qkv + (size_t)bb * 1024 * 3072 + h * 64;
    const int tid = threadIdx.x;
    const int tx = tid & 15, ty = tid >> 4;

    __shared__ float qs[32][65];
    __shared__ float ks[64][65];
    __shared__ float vs[64][65];
    __shared__ float ps[32][65];

    {   // load Q tile (scaled by 1/sqrt(64))
        const int c4 = tid & 15, r = tid >> 4;
        #pragma unroll
        for (int g = 0; g < 2; g++) {
            const int row = r + 16 * g;
            const float4 v = *(const float4*)(base + (size_t)(qt * 32 + row) * 3072 + c4 * 4);
            qs[row][c4*4+0] = v.x * 0.125f;
            qs[row][c4*4+1] = v.y * 0.125f;
            qs[row][c4*4+2] = v.z * 0.125f;
            qs[row][c4*4+3] = v.w * 0.125f;
        }
    }

    float m_i[2] = {-1e30f, -1e30f};
    float l_i[2] = {0.f, 0.f};
    float oacc[2][4] = {};

    const int kt_max = (qt * 32 + 31) >> 6;
    for (int kt = 0; kt <= kt_max; kt++) {
        __syncthreads();          // prev tile's LDS reads done
        {   // load K, V tiles
            const int c4 = tid & 15, r = tid >> 4;
            #pragma unroll
            for (int g = 0; g < 4; g++) {
                const int row = r + 16 * g;
                const float* rp = base + (size_t)(kt * 64 + row) * 3072;
                const float4 kv = *(const float4*)(rp + 1024 + c4 * 4);
                const float4 vv = *(const float4*)(rp + 2048 + c4 * 4);
                ks[row][c4*4+0] = kv.x; ks[row][c4*4+1] = kv.y;
                ks[row][c4*4+2] = kv.z; ks[row][c4*4+3] = kv.w;
                vs[row][c4*4+0] = vv.x; vs[row][c4*4+1] = vv.y;
                vs[row][c4*4+2] = vv.z; vs[row][c4*4+3] = vv.w;
            }
        }
        __syncthreads();

        float s[2][4] = {};
        #pragma unroll 8
        for (int d = 0; d < 64; d++) {
            const float a0 = qs[ty*2+0][d];
            const float a1 = qs[ty*2+1][d];
            const float b0 = ks[tx*4+0][d];
            const float b1 = ks[tx*4+1][d];
            const float b2 = ks[tx*4+2][d];
            const float b3 = ks[tx*4+3][d];
            s[0][0] += a0*b0; s[0][1] += a0*b1; s[0][2] += a0*b2; s[0][3] += a0*b3;
            s[1][0] += a1*b0; s[1][1] += a1*b1; s[1][2] += a1*b2; s[1][3] += a1*b3;
        }

        // softcap + causal mask
        #pragma unroll
        for (int i = 0; i < 2; i++) {
            const int grow = qt * 32 + ty * 2 + i;
            #pragma unroll
            for (int j = 0; j < 4; j++) {
                const int gcol = kt * 64 + tx * 4 + j;
                const float sc = 6.0f * tanhf(s[i][j] * (1.0f / 6.0f));
                s[i][j] = (gcol > grow) ? -1e30f : sc;
            }
        }

        // online softmax (rows pinned to this thread across tiles)
        #pragma unroll
        for (int i = 0; i < 2; i++) {
            float mx = fmaxf(fmaxf(s[i][0], s[i][1]), fmaxf(s[i][2], s[i][3]));
            mx = fmaxf(mx, __shfl_xor(mx, 1, 16));
            mx = fmaxf(mx, __shfl_xor(mx, 2, 16));
            mx = fmaxf(mx, __shfl_xor(mx, 4, 16));
            mx = fmaxf(mx, __shfl_xor(mx, 8, 16));
            const float mnew = fmaxf(m_i[i], mx);
            const float alpha = __expf(m_i[i] - mnew);
            float rs = 0.f;
            #pragma unroll
            for (int j = 0; j < 4; j++) {
                const float p = __expf(s[i][j] - mnew);
                s[i][j] = p;
                rs += p;
            }
            rs += __shfl_xor(rs, 1, 16);
            rs += __shfl_xor(rs, 2, 16);
            rs += __shfl_xor(rs, 4, 16);
            rs += __shfl_xor(rs, 8, 16);
            l_i[i] = l_i[i] * alpha + rs;
            m_i[i] = mnew;
            #pragma unroll
            for (int j = 0; j < 4; j++) oacc[i][j] *= alpha;
            ps[ty*2+i][tx*4+0] = s[i][0];
            ps[ty*2+i][tx*4+1] = s[i][1];
            ps[ty*2+i][tx*4+2] = s[i][2];
            ps[ty*2+i][tx*4+3] = s[i][3];
        }
        __syncthreads();

        // O += P @ V
        #pragma unroll 8
        for (int c = 0; c < 64; c++) {
            const float p0 = ps[ty*2+0][c];
            const float p1 = ps[ty*2+1][c];
            const float v0 = vs[c][tx*4+0];
            const float v1 = vs[c][tx*4+1];
            const float v2 = vs[c][tx*4+2];
            const float v3 = vs[c][tx*4+3];
            oacc[0][0] += p0*v0; oacc[0][1] += p0*v1; oacc[0][2] += p0*v2; oacc[0][3] += p0*v3;
            oacc[1][0] += p1*v0; oacc[1][1] += p1*v1; oacc[1][2] += p1*v2; oacc[1][3] += p1*v3;
        }
    }

    #pragma unroll
    for (int i = 0; i < 2; i++) {
        const float inv_l = 1.0f / l_i[i];
        const int row = qt * 32 + ty * 2 + i;
        float* op = o + (size_t)(bb * 1024 + row) * 1024 + h * 64 + tx * 4;
        op[0] = oacc[i][0] * inv_l;
        op[1] = oacc[i][1] * inv_l;
        op[2] = oacc[i][2] * inv_l;
        op[3] = oacc[i][3] * inv_l;
    }
}

extern "C" void kernel_launch(void* const* d_in, const int* in_sizes, int n_in,
                              void* d_out, int out_size, void* d_ws, size_t ws_size,
                              hipStream_t stream)
{
    (void)in_sizes; (void)n_in; (void)out_size; (void)ws_size;
    const float* x     = (const float*)d_in[0];
    // d_in[1] = mask: deterministic causal tril — hardcoded in attn_kernel
    const float* qkv_w = (const float*)d_in[2];
    const float* qkv_b = (const float*)d_in[3];
    const float* out_w = (const float*)d_in[4];
    const float* out_b = (const float*)d_in[5];
    const float* ln1_g = (const float*)d_in[6];
    const float* ln1_b = (const float*)d_in[7];
    const float* ln2_g = (const float*)d_in[8];
    const float* ln2_b = (const float*)d_in[9];
    const float* ff1_w = (const float*)d_in[10];
    const float* ff1_b = (const float*)d_in[11];
    const float* ff2_w = (const float*)d_in[12];
    const float* ff2_b = (const float*)d_in[13];
    float* out = (float*)d_out;

    // workspace: qkv (12.58M f, reused for FF1 out) | h (4.19M f) | o (4.19M f) = 84 MB
    float* qkv = (float*)d_ws;
    float* h   = qkv + (size_t)NROWS * 3072;
    float* o   = h   + (size_t)NROWS * 1024;

    // 1) h = LN1(x)
    ln_kernel<<<NROWS, 256, 0, stream>>>(x, ln1_g, ln1_b, h);
    // 2) qkv = h @ qkv_w^T + qkv_b
    gemm_kernel<<<dim3(3072/128, NROWS/128), 256, 0, stream>>>(h, qkv_w, qkv_b, nullptr, qkv, 3072, 1024, 0);
    // 3) o = attention(qkv)
    attn_kernel<<<dim3(32, 64), 256, 0, stream>>>(qkv, o);
    // 4) out = x + o @ out_w^T + out_b
    gemm_kernel<<<dim3(1024/128, NROWS/128), 256, 0, stream>>>(o, out_w, out_b, x, out, 1024, 1024, 0);
    // 5) h = LN2(out)
    ln_kernel<<<NROWS, 256, 0, stream>>>(out, ln2_g, ln2_b, h);
    // 6) ff1 = gelu(h @ ff1_w^T + ff1_b)   (reuse qkv buffer)
    gemm_kernel<<<dim3(2048/128, NROWS/128), 256, 0, stream>>>(h, ff1_w, ff1_b, nullptr, qkv, 2048, 1024, 1);
    // 7) out = out + ff1 @ ff2_w^T + ff2_b
    gemm_kernel<<<dim3(1024/128, NROWS/128), 256, 0, stream>>>(qkv, ff2_w, ff2_b, out, out, 1024, 2048, 0);
}

// Round 2
// 888.508 us; speedup vs baseline: 1.7427x; 1.7427x over previous
//
#include <hip/hip_runtime.h>
#include <cmath>

#define NROWS 4096   // B*S
#define DM    1024   // model dim

typedef unsigned short u16;
typedef __attribute__((ext_vector_type(8))) short short8;   // 8 x bf16 (4 VGPRs)
typedef __attribute__((ext_vector_type(4))) float floatx4;  // MFMA accumulator

__device__ __forceinline__ u16 f2bf(float f) {              // RNE fp32->bf16
    unsigned int u = __float_as_uint(f);
    return (u16)((u + 0x7fffu + ((u >> 16) & 1u)) >> 16);
}

__device__ __forceinline__ void async_copy16(const void* g, void* l) {
    __builtin_amdgcn_global_load_lds(
        (const __attribute__((address_space(1))) void*)g,
        (__attribute__((address_space(3))) void*)l, 16, 0, 0);
}

// ---------------- fp32 -> bf16 weight cast: 4 elems/thread ----------------
__global__ __launch_bounds__(256) void castw_kernel(
    const float* __restrict__ in, u16* __restrict__ out)
{
    const int i = (blockIdx.x * 256 + threadIdx.x) * 4;
    const float4 v = *(const float4*)(in + i);
    *(ushort4*)(out + i) = make_ushort4(f2bf(v.x), f2bf(v.y), f2bf(v.z), f2bf(v.w));
}

// ---------------- LayerNorm: one block (256 thr) per row of 1024; bf16 out ----------------
__global__ __launch_bounds__(256) void ln_kernel(
    const float* __restrict__ x, const float* __restrict__ g,
    const float* __restrict__ beta, u16* __restrict__ out)
{
    const int row = blockIdx.x;
    const int t = threadIdx.x;
    const float4 v = ((const float4*)(x + (size_t)row * DM))[t];
    float s = v.x + v.y + v.z + v.w;
    #pragma unroll
    for (int off = 32; off > 0; off >>= 1) s += __shfl_xor(s, off);
    __shared__ float red[4];
    const int wid = t >> 6;
    if ((t & 63) == 0) red[wid] = s;
    __syncthreads();
    const float mean = (red[0] + red[1] + red[2] + red[3]) * (1.0f / DM);
    const float dx = v.x - mean, dy = v.y - mean, dz = v.z - mean, dw = v.w - mean;
    float ss = dx*dx + dy*dy + dz*dz + dw*dw;
    #pragma unroll
    for (int off = 32; off > 0; off >>= 1) ss += __shfl_xor(ss, off);
    __syncthreads();
    if ((t & 63) == 0) red[wid] = ss;
    __syncthreads();
    const float var = (red[0] + red[1] + red[2] + red[3]) * (1.0f / DM);
    const float rstd = rsqrtf(var + 1e-5f);
    const float4 gv = ((const float4*)g)[t];
    const float4 bv = ((const float4*)beta)[t];
    *(ushort4*)(out + (size_t)row * DM + t * 4) = make_ushort4(
        f2bf(dx * rstd * gv.x + bv.x), f2bf(dy * rstd * gv.y + bv.y),
        f2bf(dz * rstd * gv.z + bv.z), f2bf(dw * rstd * gv.w + bv.w));
}

__device__ __forceinline__ float gelu_f(float v) {
    return 0.5f * v * (1.0f + erff(v * 0.70710678118654752f));
}

// ---------------- bf16 MFMA GEMM: C[M,N] = act(A[M,K] @ W[N,K]^T + bias) (+res) --------
// 128x128 tile, BK=64, 4 waves in 2x2, each wave 4x4 grid of 16x16x32 MFMA.
// LDS holds tiles in MFMA *fragment order* (written by global_load_lds at
// wave-base + lane*16), so inner ds_read_b128 is lane*16-sequential: 0 conflicts.
template <int ACT, int BF16OUT>
__global__ __launch_bounds__(256, 2) void gemm_bf16_kernel(
    const u16* __restrict__ A, const u16* __restrict__ W,
    const float* __restrict__ bias, const float* __restrict__ res,
    void* __restrict__ Cout, int N, int K)
{
    __shared__ __align__(16) short As[8192];   // 128 rows x 64 k, fragment order, 16 KB
    __shared__ __align__(16) short Bs[8192];

    const int tid = threadIdx.x;
    const int w = tid >> 6;          // wave 0..3
    const int l = tid & 63;
    const int lr = l & 15;           // row-in-16 for staging & col-in-tile for C
    const int lq = l >> 4;           // k-chunk / quad
    const int wm = w >> 1, wn = w & 1;
    const int m0 = blockIdx.y * 128, n0 = blockIdx.x * 128;

    const u16* A_blk = A + (size_t)m0 * K;
    const u16* W_blk = W + (size_t)n0 * K;

    // staging source offsets: issue idx = w*4+j -> m_tile=idx>>1, s=idx&1
    size_t aoff[4];
    #pragma unroll
    for (int j = 0; j < 4; j++) {
        const int idx = w * 4 + j;
        const int mt = idx >> 1, s = idx & 1;
        aoff[j] = (size_t)(mt * 16 + lr) * K + s * 32 + lq * 8;
    }

    floatx4 acc[4][4] = {};

    for (int kb = 0; kb < K; kb += 64) {
        __syncthreads();   // previous tile's LDS reads complete
        #pragma unroll
        for (int j = 0; j < 4; j++) {
            const int idx = w * 4 + j;
            async_copy16(A_blk + aoff[j] + kb, &As[idx * 512]);
            async_copy16(W_blk + aoff[j] + kb, &Bs[idx * 512]);
        }
        __syncthreads();   // staged (compiler drains vmcnt before barrier)

        #pragma unroll
        for (int s = 0; s < 2; s++) {
            short8 af[4], bfr[4];
            #pragma unroll
            for (int i = 0; i < 4; i++)
                af[i] = *(const short8*)&As[(((4 * wm + i) * 2 + s) * 64 + l) * 8];
            #pragma unroll
            for (int j = 0; j < 4; j++)
                bfr[j] = *(const short8*)&Bs[(((4 * wn + j) * 2 + s) * 64 + l) * 8];
            #pragma unroll
            for (int i = 0; i < 4; i++)
                #pragma unroll
                for (int j = 0; j < 4; j++)
                    acc[i][j] = __builtin_amdgcn_mfma_f32_16x16x32_bf16(
                        af[i], bfr[j], acc[i][j], 0, 0, 0);
        }
    }

    // epilogue: C/D layout col = lane&15, row = (lane>>4)*4 + reg
    float bj[4];
    #pragma unroll
    for (int j = 0; j < 4; j++) bj[j] = bias[n0 + wn * 64 + j * 16 + lr];

    #pragma unroll
    for (int i = 0; i < 4; i++) {
        #pragma unroll
        for (int r = 0; r < 4; r++) {
            const int row = m0 + wm * 64 + i * 16 + lq * 4 + r;
            const size_t rowoff = (size_t)row * N;
            #pragma unroll
            for (int j = 0; j < 4; j++) {
                const int col = n0 + wn * 64 + j * 16 + lr;
                float v = acc[i][j][r] + bj[j];
                if (ACT) v = gelu_f(v);
                if (res) v += res[rowoff + col];
                if (BF16OUT) ((u16*)Cout)[rowoff + col] = f2bf(v);
                else         ((float*)Cout)[rowoff + col] = v;
            }
        }
    }
}

// ---------------- Flash attention, fp32, causal, softcap 6*tanh(s/6); bf16 out --------
__global__ __launch_bounds__(256, 2) void attn_kernel(
    const float* __restrict__ qkv, u16* __restrict__ o)
{
    const int qt = blockIdx.x;   // 0..31
    const int bh = blockIdx.y;   // 0..63
    const int bb = bh >> 4, h = bh & 15;
    const float* base = qkv + (size_t)bb * 1024 * 3072 + h * 64;
    const int tid = threadIdx.x;
    const int tx = tid & 15, ty = tid >> 4;

    __shared__ float qs[32][65];
    __shared__ float ks[64][65];
    __shared__ float vs[64][65];
    __shared__ float ps[32][65];

    {   // load Q tile (scaled by 1/sqrt(64))
        const int c4 = tid & 15, r = tid >> 4;
        #pragma unroll
        for (int g = 0; g < 2; g++) {
            const int row = r + 16 * g;
            const float4 v = *(const float4*)(base + (size_t)(qt * 32 + row) * 3072 + c4 * 4);
            qs[row][c4*4+0] = v.x * 0.125f;
            qs[row][c4*4+1] = v.y * 0.125f;
            qs[row][c4*4+2] = v.z * 0.125f;
            qs[row][c4*4+3] = v.w * 0.125f;
        }
    }

    float m_i[2] = {-1e30f, -1e30f};
    float l_i[2] = {0.f, 0.f};
    float oacc[2][4] = {};

    const int kt_max = (qt * 32 + 31) >> 6;
    for (int kt = 0; kt <= kt_max; kt++) {
        __syncthreads();
        {   // load K, V tiles
            const int c4 = tid & 15, r = tid >> 4;
            #pragma unroll
            for (int g = 0; g < 4; g++) {
                const int row = r + 16 * g;
                const float* rp = base + (size_t)(kt * 64 + row) * 3072;
                const float4 kv = *(const float4*)(rp + 1024 + c4 * 4);
                const float4 vv = *(const float4*)(rp + 2048 + c4 * 4);
                ks[row][c4*4+0] = kv.x; ks[row][c4*4+1] = kv.y;
                ks[row][c4*4+2] = kv.z; ks[row][c4*4+3] = kv.w;
                vs[row][c4*4+0] = vv.x; vs[row][c4*4+1] = vv.y;
                vs[row][c4*4+2] = vv.z; vs[row][c4*4+3] = vv.w;
            }
        }
        __syncthreads();

        float s[2][4] = {};
        #pragma unroll 8
        for (int d = 0; d < 64; d++) {
            const float a0 = qs[ty*2+0][d];
            const float a1 = qs[ty*2+1][d];
            const float b0 = ks[tx*4+0][d];
            const float b1 = ks[tx*4+1][d];
            const float b2 = ks[tx*4+2][d];
            const float b3 = ks[tx*4+3][d];
            s[0][0] += a0*b0; s[0][1] += a0*b1; s[0][2] += a0*b2; s[0][3] += a0*b3;
            s[1][0] += a1*b0; s[1][1] += a1*b1; s[1][2] += a1*b2; s[1][3] += a1*b3;
        }

        #pragma unroll
        for (int i = 0; i < 2; i++) {
            const int grow = qt * 32 + ty * 2 + i;
            #pragma unroll
            for (int j = 0; j < 4; j++) {
                const int gcol = kt * 64 + tx * 4 + j;
                const float sc = 6.0f * tanhf(s[i][j] * (1.0f / 6.0f));
                s[i][j] = (gcol > grow) ? -1e30f : sc;
            }
        }

        #pragma unroll
        for (int i = 0; i < 2; i++) {
            float mx = fmaxf(fmaxf(s[i][0], s[i][1]), fmaxf(s[i][2], s[i][3]));
            mx = fmaxf(mx, __shfl_xor(mx, 1, 16));
            mx = fmaxf(mx, __shfl_xor(mx, 2, 16));
            mx = fmaxf(mx, __shfl_xor(mx, 4, 16));
            mx = fmaxf(mx, __shfl_xor(mx, 8, 16));
            const float mnew = fmaxf(m_i[i], mx);
            const float alpha = __expf(m_i[i] - mnew);
            float rs = 0.f;
            #pragma unroll
            for (int j = 0; j < 4; j++) {
                const float p = __expf(s[i][j] - mnew);
                s[i][j] = p;
                rs += p;
            }
            rs += __shfl_xor(rs, 1, 16);
            rs += __shfl_xor(rs, 2, 16);
            rs += __shfl_xor(rs, 4, 16);
            rs += __shfl_xor(rs, 8, 16);
            l_i[i] = l_i[i] * alpha + rs;
            m_i[i] = mnew;
            #pragma unroll
            for (int j = 0; j < 4; j++) oacc[i][j] *= alpha;
            ps[ty*2+i][tx*4+0] = s[i][0];
            ps[ty*2+i][tx*4+1] = s[i][1];
            ps[ty*2+i][tx*4+2] = s[i][2];
            ps[ty*2+i][tx*4+3] = s[i][3];
        }
        __syncthreads();

        #pragma unroll 8
        for (int c = 0; c < 64; c++) {
            const float p0 = ps[ty*2+0][c];
            const float p1 = ps[ty*2+1][c];
            const float v0 = vs[c][tx*4+0];
            const float v1 = vs[c][tx*4+1];
            const float v2 = vs[c][tx*4+2];
            const float v3 = vs[c][tx*4+3];
            oacc[0][0] += p0*v0; oacc[0][1] += p0*v1; oacc[0][2] += p0*v2; oacc[0][3] += p0*v3;
            oacc[1][0] += p1*v0; oacc[1][1] += p1*v1; oacc[1][2] += p1*v2; oacc[1][3] += p1*v3;
        }
    }

    #pragma unroll
    for (int i = 0; i < 2; i++) {
        const float inv_l = 1.0f / l_i[i];
        const int row = qt * 32 + ty * 2 + i;
        u16* op = o + (size_t)(bb * 1024 + row) * 1024 + h * 64 + tx * 4;
        *(ushort4*)op = make_ushort4(
            f2bf(oacc[i][0] * inv_l), f2bf(oacc[i][1] * inv_l),
            f2bf(oacc[i][2] * inv_l), f2bf(oacc[i][3] * inv_l));
    }
}

extern "C" void kernel_launch(void* const* d_in, const int* in_sizes, int n_in,
                              void* d_out, int out_size, void* d_ws, size_t ws_size,
                              hipStream_t stream)
{
    (void)in_sizes; (void)n_in; (void)out_size; (void)ws_size;
    const float* x     = (const float*)d_in[0];
    // d_in[1] = mask: deterministic causal tril — hardcoded in attn_kernel
    const float* qkv_w = (const float*)d_in[2];
    const float* qkv_b = (const float*)d_in[3];
    const float* out_w = (const float*)d_in[4];
    const float* out_b = (const float*)d_in[5];
    const float* ln1_g = (const float*)d_in[6];
    const float* ln1_b = (const float*)d_in[7];
    const float* ln2_g = (const float*)d_in[8];
    const float* ln2_b = (const float*)d_in[9];
    const float* ff1_w = (const float*)d_in[10];
    const float* ff1_b = (const float*)d_in[11];
    const float* ff2_w = (const float*)d_in[12];
    const float* ff2_b = (const float*)d_in[13];
    float* out = (float*)d_out;

    // workspace layout (83,886,080 B total):
    //   [0, 50.3MB)   qkv fp32 (4096x3072)    -- later reused for ff1 bf16
    //   [50.3, 58.7)  h  bf16 (4096x1024)
    //   [58.7, 67.1)  o  bf16 (4096x1024)
    //   [67.1, 83.9)  weights bf16 (8,388,608 elems)
    float* qkvbuf = (float*)d_ws;
    u16* hbuf = (u16*)((char*)d_ws + 50331648);
    u16* obuf = (u16*)((char*)d_ws + 58720256);
    u16* wq = (u16*)((char*)d_ws + 67108864);
    u16* wo = wq + 3145728;
    u16* w1 = wo + 1048576;
    u16* w2 = w1 + 2097152;
    u16* ff1buf = (u16*)d_ws;    // overlaps qkvbuf (qkv dead after attention)

    // weight casts (fp32 -> bf16), every call (ws is re-poisoned)
    castw_kernel<<<3072, 256, 0, stream>>>(qkv_w, wq);
    castw_kernel<<<1024, 256, 0, stream>>>(out_w, wo);
    castw_kernel<<<2048, 256, 0, stream>>>(ff1_w, w1);
    castw_kernel<<<2048, 256, 0, stream>>>(ff2_w, w2);

    // 1) h = LN1(x)  [bf16]
    ln_kernel<<<NROWS, 256, 0, stream>>>(x, ln1_g, ln1_b, hbuf);
    // 2) qkv = h @ qkv_w^T + qkv_b  [fp32 out]
    gemm_bf16_kernel<0,0><<<dim3(3072/128, NROWS/128), 256, 0, stream>>>(
        hbuf, wq, qkv_b, nullptr, qkvbuf, 3072, 1024);
    // 3) o = attention(qkv)  [bf16 out]
    attn_kernel<<<dim3(32, 64), 256, 0, stream>>>(qkvbuf, obuf);
    // 4) out = x + o @ out_w^T + out_b  [fp32]
    gemm_bf16_kernel<0,0><<<dim3(1024/128, NROWS/128), 256, 0, stream>>>(
        obuf, wo, out_b, x, out, 1024, 1024);
    // 5) h = LN2(out)  [bf16]
    ln_kernel<<<NROWS, 256, 0, stream>>>(out, ln2_g, ln2_b, hbuf);
    // 6) ff1 = gelu(h @ ff1_w^T + ff1_b)  [bf16 out]
    gemm_bf16_kernel<1,1><<<dim3(2048/128, NROWS/128), 256, 0, stream>>>(
        hbuf, w1, ff1_b, nullptr, ff1buf, 2048, 1024);
    // 7) out = out + ff1 @ ff2_w^T + ff2_b  [fp32]
    gemm_bf16_kernel<0,0><<<dim3(1024/128, NROWS/128), 256, 0, stream>>>(
        ff1buf, w2, ff2_b, out, out, 1024, 2048);
}

// Round 3
// 409.556 us; speedup vs baseline: 3.7806x; 2.1694x over previous
//
#include <hip/hip_runtime.h>
#include <cmath>

#define NROWS 4096   // B*S
#define DM    1024   // model dim

typedef unsigned short u16;
typedef __attribute__((ext_vector_type(8))) short short8;   // 8 x bf16 (4 VGPRs)
typedef __attribute__((ext_vector_type(4))) float floatx4;  // MFMA accumulator

__device__ __forceinline__ u16 f2bf(float f) {              // RNE fp32->bf16
    unsigned int u = __float_as_uint(f);
    return (u16)((u + 0x7fffu + ((u >> 16) & 1u)) >> 16);
}

__device__ __forceinline__ void async_copy16(const void* g, void* l) {
    __builtin_amdgcn_global_load_lds(
        (const __attribute__((address_space(1))) void*)g,
        (__attribute__((address_space(3))) void*)l, 16, 0, 0);
}

// ---------------- fp32 -> bf16 weight cast: 4 elems/thread ----------------
__global__ __launch_bounds__(256) void castw_kernel(
    const float* __restrict__ in, u16* __restrict__ out)
{
    const int i = (blockIdx.x * 256 + threadIdx.x) * 4;
    const float4 v = *(const float4*)(in + i);
    *(ushort4*)(out + i) = make_ushort4(f2bf(v.x), f2bf(v.y), f2bf(v.z), f2bf(v.w));
}

// ---------------- LayerNorm: one block (256 thr) per row of 1024; bf16 out ----------------
__global__ __launch_bounds__(256) void ln_kernel(
    const float* __restrict__ x, const float* __restrict__ g,
    const float* __restrict__ beta, u16* __restrict__ out)
{
    const int row = blockIdx.x;
    const int t = threadIdx.x;
    const float4 v = ((const float4*)(x + (size_t)row * DM))[t];
    float s = v.x + v.y + v.z + v.w;
    #pragma unroll
    for (int off = 32; off > 0; off >>= 1) s += __shfl_xor(s, off);
    __shared__ float red[4];
    const int wid = t >> 6;
    if ((t & 63) == 0) red[wid] = s;
    __syncthreads();
    const float mean = (red[0] + red[1] + red[2] + red[3]) * (1.0f / DM);
    const float dx = v.x - mean, dy = v.y - mean, dz = v.z - mean, dw = v.w - mean;
    float ss = dx*dx + dy*dy + dz*dz + dw*dw;
    #pragma unroll
    for (int off = 32; off > 0; off >>= 1) ss += __shfl_xor(ss, off);
    __syncthreads();
    if ((t & 63) == 0) red[wid] = ss;
    __syncthreads();
    const float var = (red[0] + red[1] + red[2] + red[3]) * (1.0f / DM);
    const float rstd = rsqrtf(var + 1e-5f);
    const float4 gv = ((const float4*)g)[t];
    const float4 bv = ((const float4*)beta)[t];
    *(ushort4*)(out + (size_t)row * DM + t * 4) = make_ushort4(
        f2bf(dx * rstd * gv.x + bv.x), f2bf(dy * rstd * gv.y + bv.y),
        f2bf(dz * rstd * gv.z + bv.z), f2bf(dw * rstd * gv.w + bv.w));
}

__device__ __forceinline__ float gelu_f(float v) {
    return 0.5f * v * (1.0f + erff(v * 0.70710678118654752f));
}

// ---------------- bf16 MFMA GEMM: C[M,N] = act(A[M,K] @ W[N,K]^T + bias) (+res) --------
// 128x128 tile, BK=64, 4 waves in 2x2, each wave 4x4 grid of 16x16x32 MFMA.
// VSPLIT: column-blocks with n0>=2048 (the V part of QKV) are written TRANSPOSED
// to vtout as Vt[b][h][d][s] so attention can stage V in MFMA B-fragment order.
template <int ACT, int BF16OUT, int VSPLIT>
__global__ __launch_bounds__(256, 2) void gemm_bf16_kernel(
    const u16* __restrict__ A, const u16* __restrict__ W,
    const float* __restrict__ bias, const float* __restrict__ res,
    void* __restrict__ Cout, u16* __restrict__ vtout, int N, int K)
{
    __shared__ __align__(16) short As[8192];   // 128 rows x 64 k, fragment order, 16 KB
    __shared__ __align__(16) short Bs[8192];

    const int tid = threadIdx.x;
    const int w = tid >> 6;          // wave 0..3
    const int l = tid & 63;
    const int lr = l & 15;
    const int lq = l >> 4;
    const int wm = w >> 1, wn = w & 1;
    const int m0 = blockIdx.y * 128, n0 = blockIdx.x * 128;

    const u16* A_blk = A + (size_t)m0 * K;
    const u16* W_blk = W + (size_t)n0 * K;

    size_t aoff[4];
    #pragma unroll
    for (int j = 0; j < 4; j++) {
        const int idx = w * 4 + j;
        const int mt = idx >> 1, s = idx & 1;
        aoff[j] = (size_t)(mt * 16 + lr) * K + s * 32 + lq * 8;
    }

    floatx4 acc[4][4] = {};

    for (int kb = 0; kb < K; kb += 64) {
        __syncthreads();
        #pragma unroll
        for (int j = 0; j < 4; j++) {
            const int idx = w * 4 + j;
            async_copy16(A_blk + aoff[j] + kb, &As[idx * 512]);
            async_copy16(W_blk + aoff[j] + kb, &Bs[idx * 512]);
        }
        __syncthreads();

        #pragma unroll
        for (int s = 0; s < 2; s++) {
            short8 af[4], bfr[4];
            #pragma unroll
            for (int i = 0; i < 4; i++)
                af[i] = *(const short8*)&As[(((4 * wm + i) * 2 + s) * 64 + l) * 8];
            #pragma unroll
            for (int j = 0; j < 4; j++)
                bfr[j] = *(const short8*)&Bs[(((4 * wn + j) * 2 + s) * 64 + l) * 8];
            #pragma unroll
            for (int i = 0; i < 4; i++)
                #pragma unroll
                for (int j = 0; j < 4; j++)
                    acc[i][j] = __builtin_amdgcn_mfma_f32_16x16x32_bf16(
                        af[i], bfr[j], acc[i][j], 0, 0, 0);
        }
    }

    float bj[4];
    #pragma unroll
    for (int j = 0; j < 4; j++) bj[j] = bias[n0 + wn * 64 + j * 16 + lr];

    if (VSPLIT && n0 >= 2048) {
        // V-part: write transposed Vt[((b*16+h)*64+d)*1024 + spos]
        #pragma unroll
        for (int i = 0; i < 4; i++)
            #pragma unroll
            for (int r = 0; r < 4; r++) {
                const int row = m0 + wm * 64 + i * 16 + lq * 4 + r;  // b*1024+spos
                const int bidx = row >> 10, spos = row & 1023;
                #pragma unroll
                for (int j = 0; j < 4; j++) {
                    const int vcol = (n0 - 2048) + wn * 64 + j * 16 + lr; // h*64+d
                    const float v = acc[i][j][r] + bj[j];
                    vtout[((size_t)(bidx * 16 + (vcol >> 6)) * 64 + (vcol & 63)) * 1024 + spos]
                        = f2bf(v);
                }
            }
        return;
    }

    #pragma unroll
    for (int i = 0; i < 4; i++) {
        #pragma unroll
        for (int r = 0; r < 4; r++) {
            const int row = m0 + wm * 64 + i * 16 + lq * 4 + r;
            const size_t rowoff = (size_t)row * N;
            #pragma unroll
            for (int j = 0; j < 4; j++) {
                const int col = n0 + wn * 64 + j * 16 + lr;
                float v = acc[i][j][r] + bj[j];
                if (ACT) v = gelu_f(v);
                if (res) v += res[rowoff + col];
                if (BF16OUT) ((u16*)Cout)[rowoff + col] = f2bf(v);
                else         ((float*)Cout)[rowoff + col] = v;
            }
        }
    }
}

// ---------------- MFMA flash attention, bf16 in, causal, softcap 6*tanh(s/6) ----------
// Q-tile 64/block (wave w owns 16 q-rows). K-tile 64. S^T = K*Q^T (C layout: col=q),
// softmax with 2 shuffles, P via per-wave LDS round-trip to A-layout, O += P*V with
// V staged from Vt in B-fragment order. Grid: (16 qt desc, 64 b*h).
__global__ __launch_bounds__(256, 4) void attn_mfma_kernel(
    const u16* __restrict__ qkv,   // [4096][3072] bf16 (Q: h*64+d, K: 1024+h*64+d)
    const u16* __restrict__ vt,    // [b][h][64][1024] bf16
    u16* __restrict__ o)           // [4096][1024] bf16
{
    __shared__ __align__(16) short Ks[4096];     // 8 KB: 8 frag-issues x 64 lanes x 8
    __shared__ __align__(16) short Vs[4096];     // 8 KB
    __shared__ __align__(16) short Ps[4][1152];  // per-wave 16 x 72 (pad): 9.2 KB

    const int qt = 15 - blockIdx.x;              // longest blocks first
    const int bh = blockIdx.y;
    const int b = bh >> 4, h = bh & 15;
    const int tid = threadIdx.x;
    const int w = tid >> 6, l = tid & 63;
    const int C = l & 15, Qd = l >> 4;

    // Q register fragment (B-operand): lane holds Q[q=C][d=Qd*8+j+32s]
    short8 qf[2];
    {
        const u16* qp = qkv + (size_t)(b * 1024 + qt * 64 + w * 16 + C) * 3072 + h * 64 + Qd * 8;
        qf[0] = *(const short8*)qp;
        qf[1] = *(const short8*)(qp + 32);
    }

    const u16* kbase = qkv + (size_t)(b * 1024) * 3072 + 1024 + h * 64;
    const u16* vbase = vt + (size_t)(b * 16 + h) * 65536;

    float m_i = -1e30f, l_i = 0.f;
    floatx4 oacc[4] = {};

    for (int kt = 0; kt <= qt; kt++) {
        __syncthreads();   // prev iteration's K/V reads done
        #pragma unroll
        for (int ii = 0; ii < 4; ii++) {
            const int i = w * 4 + ii;            // 16 issues over 4 waves
            if (i < 8) {                         // K tile, A-fragment order
                const int mt = i >> 1, s = i & 1;
                async_copy16(kbase + (size_t)(kt * 64 + mt * 16 + C) * 3072 + s * 32 + Qd * 8,
                             &Ks[i * 512]);
            } else {                             // V tile, B-fragment order
                const int j = i - 8, dt = j >> 1, s = j & 1;
                async_copy16(vbase + (size_t)(dt * 16 + C) * 1024 + kt * 64 + s * 32 + Qd * 8,
                             &Vs[j * 512]);
            }
        }
        __syncthreads();

        // S^T tiles: C[krow][q], 4 m-tiles of 16 krows
        floatx4 sacc[4] = {};
        #pragma unroll
        for (int mt = 0; mt < 4; mt++)
            #pragma unroll
            for (int s = 0; s < 2; s++) {
                const short8 kf = *(const short8*)&Ks[((mt * 2 + s) * 64 + l) * 8];
                sacc[mt] = __builtin_amdgcn_mfma_f32_16x16x32_bf16(kf, qf[s], sacc[mt], 0, 0, 0);
            }

        // scale + softcap + (diagonal) mask; per-lane 16 values, all for q = C
        float p[16];
        float tmax = -1e30f;
        const bool diag = (kt == qt);
        const int qrow = qt * 64 + w * 16 + C;
        #pragma unroll
        for (int mt = 0; mt < 4; mt++)
            #pragma unroll
            for (int r = 0; r < 4; r++) {
                const float sv = sacc[mt][r] * 0.125f;
                const float e = __expf(sv * (1.0f / 3.0f));   // e^{2x}, x = sv/6
                float sc = 6.0f - 12.0f / (e + 1.0f);         // 6*tanh(sv/6), overflow-safe
                if (diag) {
                    const int krow = kt * 64 + mt * 16 + Qd * 4 + r;
                    if (krow > qrow) sc = -1e30f;
                }
                p[mt * 4 + r] = sc;
                tmax = fmaxf(tmax, sc);
            }
        tmax = fmaxf(tmax, __shfl_xor(tmax, 16));
        tmax = fmaxf(tmax, __shfl_xor(tmax, 32));
        const float mnew = fmaxf(m_i, tmax);
        const float alpha = __expf(m_i - mnew);
        float rs = 0.f;
        #pragma unroll
        for (int i = 0; i < 16; i++) { p[i] = __expf(p[i] - mnew); rs += p[i]; }
        rs += __shfl_xor(rs, 16);
        rs += __shfl_xor(rs, 32);
        l_i = l_i * alpha + rs;
        m_i = mnew;

        // rescale O: lane's O rows are q = Qd*4+r -> fetch alpha from lane (Qd*4+r)
        float av[4];
        #pragma unroll
        for (int r = 0; r < 4; r++) av[r] = __shfl(alpha, Qd * 4 + r);
        #pragma unroll
        for (int dt = 0; dt < 4; dt++)
            #pragma unroll
            for (int r = 0; r < 4; r++) oacc[dt][r] *= av[r];

        // P (C-layout) -> per-wave LDS [q][k], padded stride 72 -> A-fragments
        #pragma unroll
        for (int mt = 0; mt < 4; mt++)
            #pragma unroll
            for (int pr = 0; pr < 2; pr++) {
                const unsigned int pk =
                    (unsigned)f2bf(p[mt * 4 + pr * 2]) |
                    ((unsigned)f2bf(p[mt * 4 + pr * 2 + 1]) << 16);
                *(unsigned int*)&Ps[w][C * 72 + mt * 16 + Qd * 4 + pr * 2] = pk;
            }
        short8 pf[2];
        pf[0] = *(const short8*)&Ps[w][C * 72 + Qd * 8];
        pf[1] = *(const short8*)&Ps[w][C * 72 + 32 + Qd * 8];

        // O += P @ V
        #pragma unroll
        for (int dt = 0; dt < 4; dt++)
            #pragma unroll
            for (int s = 0; s < 2; s++) {
                const short8 vf = *(const short8*)&Vs[((dt * 2 + s) * 64 + l) * 8];
                oacc[dt] = __builtin_amdgcn_mfma_f32_16x16x32_bf16(pf[s], vf, oacc[dt], 0, 0, 0);
            }
    }

    // epilogue: O C-layout row q = Qd*4+r, col d = dt*16+C; divide by l[q]
    float linv[4];
    #pragma unroll
    for (int r = 0; r < 4; r++) linv[r] = 1.0f / __shfl(l_i, Qd * 4 + r);
    #pragma unroll
    for (int dt = 0; dt < 4; dt++)
        #pragma unroll
        for (int r = 0; r < 4; r++) {
            const size_t row = (size_t)(b * 1024 + qt * 64 + w * 16 + Qd * 4 + r);
            o[row * 1024 + h * 64 + dt * 16 + C] = f2bf(oacc[dt][r] * linv[r]);
        }
}

extern "C" void kernel_launch(void* const* d_in, const int* in_sizes, int n_in,
                              void* d_out, int out_size, void* d_ws, size_t ws_size,
                              hipStream_t stream)
{
    (void)in_sizes; (void)n_in; (void)out_size; (void)ws_size;
    const float* x     = (const float*)d_in[0];
    // d_in[1] = mask: deterministic causal tril — hardcoded in attn kernel
    const float* qkv_w = (const float*)d_in[2];
    const float* qkv_b = (const float*)d_in[3];
    const float* out_w = (const float*)d_in[4];
    const float* out_b = (const float*)d_in[5];
    const float* ln1_g = (const float*)d_in[6];
    const float* ln1_b = (const float*)d_in[7];
    const float* ln2_g = (const float*)d_in[8];
    const float* ln2_b = (const float*)d_in[9];
    const float* ff1_w = (const float*)d_in[10];
    const float* ff1_b = (const float*)d_in[11];
    const float* ff2_w = (const float*)d_in[12];
    const float* ff2_b = (const float*)d_in[13];
    float* out = (float*)d_out;

    // workspace layout (<= 67.1 MB of 84):
    //   [0, 25.2MB)    qkv bf16 4096x3072 (V cols unused; later reused for ff1 out)
    //   [25.2, 33.6)   Vt bf16 [4][16][64][1024]
    //   [33.6, 41.9)   h  bf16 4096x1024
    //   [41.9, 50.3)   o  bf16 4096x1024
    //   [50.3, 67.1)   weights bf16
    u16* qkvbuf = (u16*)d_ws;
    u16* vtbuf  = (u16*)((char*)d_ws + 25165824);
    u16* hbuf   = (u16*)((char*)d_ws + 33554432);
    u16* obuf   = (u16*)((char*)d_ws + 41943040);
    u16* wq     = (u16*)((char*)d_ws + 50331648);
    u16* wo = wq + 3145728;
    u16* w1 = wo + 1048576;
    u16* w2 = w1 + 2097152;
    u16* ff1buf = qkvbuf;   // qkv dead after attention

    castw_kernel<<<3072, 256, 0, stream>>>(qkv_w, wq);
    castw_kernel<<<1024, 256, 0, stream>>>(out_w, wo);
    castw_kernel<<<2048, 256, 0, stream>>>(ff1_w, w1);
    castw_kernel<<<2048, 256, 0, stream>>>(ff2_w, w2);

    // 1) h = LN1(x)
    ln_kernel<<<NROWS, 256, 0, stream>>>(x, ln1_g, ln1_b, hbuf);
    // 2) qkv = h @ qkv_w^T + qkv_b  [bf16; V part written transposed to Vt]
    gemm_bf16_kernel<0,1,1><<<dim3(3072/128, NROWS/128), 256, 0, stream>>>(
        hbuf, wq, qkv_b, nullptr, qkvbuf, vtbuf, 3072, 1024);
    // 3) o = attention(q, k, Vt)
    attn_mfma_kernel<<<dim3(16, 64), 256, 0, stream>>>(qkvbuf, vtbuf, obuf);
    // 4) out = x + o @ out_w^T + out_b  [fp32]
    gemm_bf16_kernel<0,0,0><<<dim3(1024/128, NROWS/128), 256, 0, stream>>>(
        obuf, wo, out_b, x, out, nullptr, 1024, 1024);
    // 5) h = LN2(out)
    ln_kernel<<<NROWS, 256, 0, stream>>>(out, ln2_g, ln2_b, hbuf);
    // 6) ff1 = gelu(h @ ff1_w^T + ff1_b)  [bf16]
    gemm_bf16_kernel<1,1,0><<<dim3(2048/128, NROWS/128), 256, 0, stream>>>(
        hbuf, w1, ff1_b, nullptr, ff1buf, nullptr, 2048, 1024);
    // 7) out = out + ff1 @ ff2_w^T + ff2_b  [fp32]
    gemm_bf16_kernel<0,0,0><<<dim3(1024/128, NROWS/128), 256, 0, stream>>>(
        ff1buf, w2, ff2_b, out, out, nullptr, 1024, 2048);
}

// Round 4
// 367.462 us; speedup vs baseline: 4.2137x; 1.1146x over previous
//
#include <hip/hip_runtime.h>
#include <cmath>

#define NROWS 4096   // B*S
#define DM    1024   // model dim

typedef unsigned short u16;
typedef __attribute__((ext_vector_type(8))) short short8;   // 8 x bf16 (4 VGPRs)
typedef __attribute__((ext_vector_type(4))) float floatx4;  // MFMA accumulator

__device__ __forceinline__ u16 f2bf(float f) {              // RNE fp32->bf16
    unsigned int u = __float_as_uint(f);
    return (u16)((u + 0x7fffu + ((u >> 16) & 1u)) >> 16);
}

__device__ __forceinline__ void async_copy16(const void* g, void* l) {
    __builtin_amdgcn_global_load_lds(
        (const __attribute__((address_space(1))) void*)g,
        (__attribute__((address_space(3))) void*)l, 16, 0, 0);
}

// ---------------- fp32 -> bf16 weight cast: 4 elems/thread ----------------
__global__ __launch_bounds__(256) void castw_kernel(
    const float* __restrict__ in, u16* __restrict__ out)
{
    const int i = (blockIdx.x * 256 + threadIdx.x) * 4;
    const float4 v = *(const float4*)(in + i);
    *(ushort4*)(out + i) = make_ushort4(f2bf(v.x), f2bf(v.y), f2bf(v.z), f2bf(v.w));
}

// ---------------- LayerNorm: one block (256 thr) per row of 1024; bf16 out ----------------
__global__ __launch_bounds__(256) void ln_kernel(
    const float* __restrict__ x, const float* __restrict__ g,
    const float* __restrict__ beta, u16* __restrict__ out)
{
    const int row = blockIdx.x;
    const int t = threadIdx.x;
    const float4 v = ((const float4*)(x + (size_t)row * DM))[t];
    float s = v.x + v.y + v.z + v.w;
    #pragma unroll
    for (int off = 32; off > 0; off >>= 1) s += __shfl_xor(s, off);
    __shared__ float red[4];
    const int wid = t >> 6;
    if ((t & 63) == 0) red[wid] = s;
    __syncthreads();
    const float mean = (red[0] + red[1] + red[2] + red[3]) * (1.0f / DM);
    const float dx = v.x - mean, dy = v.y - mean, dz = v.z - mean, dw = v.w - mean;
    float ss = dx*dx + dy*dy + dz*dz + dw*dw;
    #pragma unroll
    for (int off = 32; off > 0; off >>= 1) ss += __shfl_xor(ss, off);
    __syncthreads();
    if ((t & 63) == 0) red[wid] = ss;
    __syncthreads();
    const float var = (red[0] + red[1] + red[2] + red[3]) * (1.0f / DM);
    const float rstd = rsqrtf(var + 1e-5f);
    const float4 gv = ((const float4*)g)[t];
    const float4 bv = ((const float4*)beta)[t];
    *(ushort4*)(out + (size_t)row * DM + t * 4) = make_ushort4(
        f2bf(dx * rstd * gv.x + bv.x), f2bf(dy * rstd * gv.y + bv.y),
        f2bf(dz * rstd * gv.z + bv.z), f2bf(dw * rstd * gv.w + bv.w));
}

__device__ __forceinline__ float gelu_f(float v) {
    return 0.5f * v * (1.0f + erff(v * 0.70710678118654752f));
}

// ---------------- bf16 MFMA GEMM: C[M,N] = act(A[M,K] @ W[N,K]^T + bias) (+res) --------
// 128x128 tile, BK=64, 4 waves 2x2, wave = 4x4 of 16x16x32 MFMA. M fixed 4096 (Mt=32).
// 1-D grid, XCD-band swizzle: xcd = fid&7 owns n-tiles [xcd*NB, (xcd+1)*NB) so W tiles
// stay in that XCD's L2. Epilogue: LDS transpose -> coalesced float4/ushort4 stores.
template <int ACT, int BF16OUT, int VSPLIT>
__global__ __launch_bounds__(256, 3) void gemm_bf16_kernel(
    const u16* __restrict__ A, const u16* __restrict__ W,
    const float* __restrict__ bias, const float* __restrict__ res,
    void* __restrict__ Cout, u16* __restrict__ vtout, int N, int K)
{
    __shared__ __align__(16) char smem[34816];
    short* As = (short*)smem;            // 16 KB staging
    short* Bs = (short*)(smem + 16384);  // 16 KB staging
    float* Cs = (float*)smem;            // 17 KB epilogue transpose (reuse)

    const int tid = threadIdx.x;
    const int w = tid >> 6;          // wave 0..3
    const int l = tid & 63;
    const int lr = l & 15;
    const int lq = l >> 4;
    const int wm = w >> 1, wn = w & 1;

    // XCD-band swizzle (Mt = 32, Nt = N/128, NB = Nt/8 n-tiles per XCD)
    const int fid = blockIdx.x;
    const int NB = (N >> 7) >> 3;
    const int xcd = fid & 7;
    const int kk = fid >> 3;
    const int nt = xcd * NB + (kk >> 5);
    const int mt = kk & 31;
    const int m0 = mt * 128, n0 = nt * 128;

    const u16* A_blk = A + (size_t)m0 * K;
    const u16* W_blk = W + (size_t)n0 * K;

    size_t aoff[4];
    #pragma unroll
    for (int j = 0; j < 4; j++) {
        const int idx = w * 4 + j;
        const int mtt = idx >> 1, s = idx & 1;
        aoff[j] = (size_t)(mtt * 16 + lr) * K + s * 32 + lq * 8;
    }

    floatx4 acc[4][4] = {};

    for (int kb = 0; kb < K; kb += 64) {
        __syncthreads();
        #pragma unroll
        for (int j = 0; j < 4; j++) {
            const int idx = w * 4 + j;
            async_copy16(A_blk + aoff[j] + kb, &As[idx * 512]);
            async_copy16(W_blk + aoff[j] + kb, &Bs[idx * 512]);
        }
        __syncthreads();

        #pragma unroll
        for (int s = 0; s < 2; s++) {
            short8 af[4], bfr[4];
            #pragma unroll
            for (int i = 0; i < 4; i++)
                af[i] = *(const short8*)&As[(((4 * wm + i) * 2 + s) * 64 + l) * 8];
            #pragma unroll
            for (int j = 0; j < 4; j++)
                bfr[j] = *(const short8*)&Bs[(((4 * wn + j) * 2 + s) * 64 + l) * 8];
            #pragma unroll
            for (int i = 0; i < 4; i++)
                #pragma unroll
                for (int j = 0; j < 4; j++)
                    acc[i][j] = __builtin_amdgcn_mfma_f32_16x16x32_bf16(
                        af[i], bfr[j], acc[i][j], 0, 0, 0);
        }
    }

    if (VSPLIT && n0 >= 2048) {
        // V-part of QKV: write transposed Vt[((b*16+h)*64+d)*1024 + spos]
        float bj[4];
        #pragma unroll
        for (int j = 0; j < 4; j++) bj[j] = bias[n0 + wn * 64 + j * 16 + lr];
        #pragma unroll
        for (int i = 0; i < 4; i++)
            #pragma unroll
            for (int r = 0; r < 4; r++) {
                const int row = m0 + wm * 64 + i * 16 + lq * 4 + r;  // b*1024+spos
                const int bidx = row >> 10, spos = row & 1023;
                #pragma unroll
                for (int j = 0; j < 4; j++) {
                    const int vcol = (n0 - 2048) + wn * 64 + j * 16 + lr; // h*64+d
                    const float v = acc[i][j][r] + bj[j];
                    vtout[((size_t)(bidx * 16 + (vcol >> 6)) * 64 + (vcol & 63)) * 1024 + spos]
                        = f2bf(v);
                }
            }
        return;
    }

    // epilogue: per m-chunk i, transpose via LDS (stride 136 floats) -> float4 rows
    #pragma unroll
    for (int i = 0; i < 4; i++) {
        __syncthreads();   // staging reads (i=0) / previous chunk reads done
        #pragma unroll
        for (int r = 0; r < 4; r++) {
            const int rl = wm * 16 + lq * 4 + r;
            #pragma unroll
            for (int j = 0; j < 4; j++)
                Cs[rl * 136 + wn * 64 + j * 16 + lr] = acc[i][j][r];
        }
        __syncthreads();
        const int rid = tid >> 3;                 // 0..31
        const int rr = m0 + (rid >> 4) * 64 + i * 16 + (rid & 15);
        const size_t rowoff = (size_t)rr * N;
        #pragma unroll
        for (int it = 0; it < 4; it++) {
            const int col = ((tid & 7) + it * 8) * 4;   // 0..124
            float4 v = *(const float4*)&Cs[rid * 136 + col];
            const float4 b4 = *(const float4*)&bias[n0 + col];
            v.x += b4.x; v.y += b4.y; v.z += b4.z; v.w += b4.w;
            if (ACT) { v.x = gelu_f(v.x); v.y = gelu_f(v.y); v.z = gelu_f(v.z); v.w = gelu_f(v.w); }
            if (res) {
                const float4 r4 = *(const float4*)&res[rowoff + n0 + col];
                v.x += r4.x; v.y += r4.y; v.z += r4.z; v.w += r4.w;
            }
            if (BF16OUT)
                *(ushort4*)((u16*)Cout + rowoff + n0 + col) =
                    make_ushort4(f2bf(v.x), f2bf(v.y), f2bf(v.z), f2bf(v.w));
            else
                *(float4*)((float*)Cout + rowoff + n0 + col) = v;
        }
    }
}

// ---------------- MFMA flash attention, bf16 in, causal, softcap 6*tanh(s/6) ----------
// grid (64 bh, 16 qt): all qt-blocks of one head share an XCD (linear%8 = bh%8)
// so K/V live in that XCD's L2. qt descending in y so longest blocks launch first.
__global__ __launch_bounds__(256, 4) void attn_mfma_kernel(
    const u16* __restrict__ qkv,   // [4096][3072] bf16 (Q: h*64+d, K: 1024+h*64+d)
    const u16* __restrict__ vt,    // [b][h][64][1024] bf16
    u16* __restrict__ o)           // [4096][1024] bf16
{
    __shared__ __align__(16) short Ks[4096];     // 8 KB
    __shared__ __align__(16) short Vs[4096];     // 8 KB
    __shared__ __align__(16) short Ps[4][1152];  // per-wave 16 x 72 (pad)

    const int qt = 15 - blockIdx.y;
    const int bh = blockIdx.x;
    const int b = bh >> 4, h = bh & 15;
    const int tid = threadIdx.x;
    const int w = tid >> 6, l = tid & 63;
    const int C = l & 15, Qd = l >> 4;

    short8 qf[2];
    {
        const u16* qp = qkv + (size_t)(b * 1024 + qt * 64 + w * 16 + C) * 3072 + h * 64 + Qd * 8;
        qf[0] = *(const short8*)qp;
        qf[1] = *(const short8*)(qp + 32);
    }

    const u16* kbase = qkv + (size_t)(b * 1024) * 3072 + 1024 + h * 64;
    const u16* vbase = vt + (size_t)(b * 16 + h) * 65536;

    float m_i = -1e30f, l_i = 0.f;
    floatx4 oacc[4] = {};

    for (int kt = 0; kt <= qt; kt++) {
        __syncthreads();
        #pragma unroll
        for (int ii = 0; ii < 4; ii++) {
            const int i = w * 4 + ii;
            if (i < 8) {
                const int mt = i >> 1, s = i & 1;
                async_copy16(kbase + (size_t)(kt * 64 + mt * 16 + C) * 3072 + s * 32 + Qd * 8,
                             &Ks[i * 512]);
            } else {
                const int j = i - 8, dt = j >> 1, s = j & 1;
                async_copy16(vbase + (size_t)(dt * 16 + C) * 1024 + kt * 64 + s * 32 + Qd * 8,
                             &Vs[j * 512]);
            }
        }
        __syncthreads();

        floatx4 sacc[4] = {};
        #pragma unroll
        for (int mt = 0; mt < 4; mt++)
            #pragma unroll
            for (int s = 0; s < 2; s++) {
                const short8 kf = *(const short8*)&Ks[((mt * 2 + s) * 64 + l) * 8];
                sacc[mt] = __builtin_amdgcn_mfma_f32_16x16x32_bf16(kf, qf[s], sacc[mt], 0, 0, 0);
            }

        float p[16];
        float tmax = -1e30f;
        const bool diag = (kt == qt);
        const int qrow = qt * 64 + w * 16 + C;
        #pragma unroll
        for (int mt = 0; mt < 4; mt++)
            #pragma unroll
            for (int r = 0; r < 4; r++) {
                const float sv = sacc[mt][r] * 0.125f;
                const float e = __expf(sv * (1.0f / 3.0f));
                float sc = 6.0f - 12.0f / (e + 1.0f);
                if (diag) {
                    const int krow = kt * 64 + mt * 16 + Qd * 4 + r;
                    if (krow > qrow) sc = -1e30f;
                }
                p[mt * 4 + r] = sc;
                tmax = fmaxf(tmax, sc);
            }
        tmax = fmaxf(tmax, __shfl_xor(tmax, 16));
        tmax = fmaxf(tmax, __shfl_xor(tmax, 32));
        const float mnew = fmaxf(m_i, tmax);
        const float alpha = __expf(m_i - mnew);
        float rs = 0.f;
        #pragma unroll
        for (int i = 0; i < 16; i++) { p[i] = __expf(p[i] - mnew); rs += p[i]; }
        rs += __shfl_xor(rs, 16);
        rs += __shfl_xor(rs, 32);
        l_i = l_i * alpha + rs;
        m_i = mnew;

        float av[4];
        #pragma unroll
        for (int r = 0; r < 4; r++) av[r] = __shfl(alpha, Qd * 4 + r);
        #pragma unroll
        for (int dt = 0; dt < 4; dt++)
            #pragma unroll
            for (int r = 0; r < 4; r++) oacc[dt][r] *= av[r];

        #pragma unroll
        for (int mt = 0; mt < 4; mt++)
            #pragma unroll
            for (int pr = 0; pr < 2; pr++) {
                const unsigned int pk =
                    (unsigned)f2bf(p[mt * 4 + pr * 2]) |
                    ((unsigned)f2bf(p[mt * 4 + pr * 2 + 1]) << 16);
                *(unsigned int*)&Ps[w][C * 72 + mt * 16 + Qd * 4 + pr * 2] = pk;
            }
        short8 pf[2];
        pf[0] = *(const short8*)&Ps[w][C * 72 + Qd * 8];
        pf[1] = *(const short8*)&Ps[w][C * 72 + 32 + Qd * 8];

        #pragma unroll
        for (int dt = 0; dt < 4; dt++)
            #pragma unroll
            for (int s = 0; s < 2; s++) {
                const short8 vf = *(const short8*)&Vs[((dt * 2 + s) * 64 + l) * 8];
                oacc[dt] = __builtin_amdgcn_mfma_f32_16x16x32_bf16(pf[s], vf, oacc[dt], 0, 0, 0);
            }
    }

    float linv[4];
    #pragma unroll
    for (int r = 0; r < 4; r++) linv[r] = 1.0f / __shfl(l_i, Qd * 4 + r);
    #pragma unroll
    for (int dt = 0; dt < 4; dt++)
        #pragma unroll
        for (int r = 0; r < 4; r++) {
            const size_t row = (size_t)(b * 1024 + qt * 64 + w * 16 + Qd * 4 + r);
            o[row * 1024 + h * 64 + dt * 16 + C] = f2bf(oacc[dt][r] * linv[r]);
        }
}

extern "C" void kernel_launch(void* const* d_in, const int* in_sizes, int n_in,
                              void* d_out, int out_size, void* d_ws, size_t ws_size,
                              hipStream_t stream)
{
    (void)in_sizes; (void)n_in; (void)out_size; (void)ws_size;
    const float* x     = (const float*)d_in[0];
    // d_in[1] = mask: deterministic causal tril — hardcoded in attn kernel
    const float* qkv_w = (const float*)d_in[2];
    const float* qkv_b = (const float*)d_in[3];
    const float* out_w = (const float*)d_in[4];
    const float* out_b = (const float*)d_in[5];
    const float* ln1_g = (const float*)d_in[6];
    const float* ln1_b = (const float*)d_in[7];
    const float* ln2_g = (const float*)d_in[8];
    const float* ln2_b = (const float*)d_in[9];
    const float* ff1_w = (const float*)d_in[10];
    const float* ff1_b = (const float*)d_in[11];
    const float* ff2_w = (const float*)d_in[12];
    const float* ff2_b = (const float*)d_in[13];
    float* out = (float*)d_out;

    u16* qkvbuf = (u16*)d_ws;
    u16* vtbuf  = (u16*)((char*)d_ws + 25165824);
    u16* hbuf   = (u16*)((char*)d_ws + 33554432);
    u16* obuf   = (u16*)((char*)d_ws + 41943040);
    u16* wq     = (u16*)((char*)d_ws + 50331648);
    u16* wo = wq + 3145728;
    u16* w1 = wo + 1048576;
    u16* w2 = w1 + 2097152;
    u16* ff1buf = qkvbuf;   // qkv dead after attention

    castw_kernel<<<3072, 256, 0, stream>>>(qkv_w, wq);
    castw_kernel<<<1024, 256, 0, stream>>>(out_w, wo);
    castw_kernel<<<2048, 256, 0, stream>>>(ff1_w, w1);
    castw_kernel<<<2048, 256, 0, stream>>>(ff2_w, w2);

    // 1) h = LN1(x)
    ln_kernel<<<NROWS, 256, 0, stream>>>(x, ln1_g, ln1_b, hbuf);
    // 2) qkv = h @ qkv_w^T + qkv_b  [bf16; V part written transposed to Vt]
    gemm_bf16_kernel<0,1,1><<<768, 256, 0, stream>>>(
        hbuf, wq, qkv_b, nullptr, qkvbuf, vtbuf, 3072, 1024);
    // 3) o = attention(q, k, Vt)
    attn_mfma_kernel<<<dim3(64, 16), 256, 0, stream>>>(qkvbuf, vtbuf, obuf);
    // 4) out = x + o @ out_w^T + out_b  [fp32]
    gemm_bf16_kernel<0,0,0><<<256, 256, 0, stream>>>(
        obuf, wo, out_b, x, out, nullptr, 1024, 1024);
    // 5) h = LN2(out)
    ln_kernel<<<NROWS, 256, 0, stream>>>(out, ln2_g, ln2_b, hbuf);
    // 6) ff1 = gelu(h @ ff1_w^T + ff1_b)  [bf16]
    gemm_bf16_kernel<1,1,0><<<512, 256, 0, stream>>>(
        hbuf, w1, ff1_b, nullptr, ff1buf, nullptr, 2048, 1024);
    // 7) out = out + ff1 @ ff2_w^T + ff2_b  [fp32]
    gemm_bf16_kernel<0,0,0><<<256, 256, 0, stream>>>(
        ff1buf, w2, ff2_b, out, out, nullptr, 1024, 2048);
}

// Round 6
// 359.105 us; speedup vs baseline: 4.3117x; 1.0233x over previous
//
#include <hip/hip_runtime.h>
#include <cmath>

#define NROWS 4096   // B*S
#define DM    1024   // model dim

typedef unsigned short u16;
typedef __attribute__((ext_vector_type(8))) short short8;   // 8 x bf16 (4 VGPRs)
typedef __attribute__((ext_vector_type(4))) float floatx4;  // MFMA accumulator

__device__ __forceinline__ u16 f2bf(float f) {              // RNE fp32->bf16
    unsigned int u = __float_as_uint(f);
    return (u16)((u + 0x7fffu + ((u >> 16) & 1u)) >> 16);
}

__device__ __forceinline__ void async_copy16(const void* g, void* l) {
    __builtin_amdgcn_global_load_lds(
        (const __attribute__((address_space(1))) void*)g,
        (__attribute__((address_space(3))) void*)l, 16, 0, 0);
}

// ---------------- fused fp32 -> bf16 weight casts (all 4 weights, 1 launch) ----------
__global__ __launch_bounds__(256) void castw4_kernel(
    const float* __restrict__ s0, const float* __restrict__ s1,
    const float* __restrict__ s2, const float* __restrict__ s3,
    u16* __restrict__ d0, u16* __restrict__ d1,
    u16* __restrict__ d2, u16* __restrict__ d3)
{
    const int bid = blockIdx.x;
    const float* s; u16* d; int base;
    if (bid < 3072)      { s = s0; d = d0; base = bid; }
    else if (bid < 4096) { s = s1; d = d1; base = bid - 3072; }
    else if (bid < 6144) { s = s2; d = d2; base = bid - 4096; }
    else                 { s = s3; d = d3; base = bid - 6144; }
    const int i = (base * 256 + threadIdx.x) * 4;
    const float4 v = *(const float4*)(s + i);
    *(ushort4*)(d + i) = make_ushort4(f2bf(v.x), f2bf(v.y), f2bf(v.z), f2bf(v.w));
}

// ---------------- LayerNorm: one block (256 thr) per row of 1024; bf16 out ----------------
__global__ __launch_bounds__(256) void ln_kernel(
    const float* __restrict__ x, const float* __restrict__ g,
    const float* __restrict__ beta, u16* __restrict__ out)
{
    const int row = blockIdx.x;
    const int t = threadIdx.x;
    const float4 v = ((const float4*)(x + (size_t)row * DM))[t];
    float s = v.x + v.y + v.z + v.w;
    #pragma unroll
    for (int off = 32; off > 0; off >>= 1) s += __shfl_xor(s, off);
    __shared__ float red[4];
    const int wid = t >> 6;
    if ((t & 63) == 0) red[wid] = s;
    __syncthreads();
    const float mean = (red[0] + red[1] + red[2] + red[3]) * (1.0f / DM);
    const float dx = v.x - mean, dy = v.y - mean, dz = v.z - mean, dw = v.w - mean;
    float ss = dx*dx + dy*dy + dz*dz + dw*dw;
    #pragma unroll
    for (int off = 32; off > 0; off >>= 1) ss += __shfl_xor(ss, off);
    __syncthreads();
    if ((t & 63) == 0) red[wid] = ss;
    __syncthreads();
    const float var = (red[0] + red[1] + red[2] + red[3]) * (1.0f / DM);
    const float rstd = rsqrtf(var + 1e-5f);
    const float4 gv = ((const float4*)g)[t];
    const float4 bv = ((const float4*)beta)[t];
    *(ushort4*)(out + (size_t)row * DM + t * 4) = make_ushort4(
        f2bf(dx * rstd * gv.x + bv.x), f2bf(dy * rstd * gv.y + bv.y),
        f2bf(dz * rstd * gv.z + bv.z), f2bf(dw * rstd * gv.w + bv.w));
}

__device__ __forceinline__ float gelu_f(float v) {
    return 0.5f * v * (1.0f + erff(v * 0.70710678118654752f));
}

// ---------------- bf16 MFMA GEMM, double-buffered staging ----------------
// 128x128 tile, BK=64, 4 waves 2x2, wave = 4x4 of 16x16x32 MFMA. M fixed 4096.
// K-loop: issue global_load_lds for tile k+1 into the OTHER LDS buffer BEFORE
// computing tile k, so the end-of-iter barrier's vmcnt(0) drain is hidden behind
// the compute phase (the round-4 single-buffer exposed ~900 cyc per iteration).
// NOTE: no pointer arrays into LDS (addrspacecast static-init is rejected on gfx950);
// buffer bases are computed from `cur` each iteration.
template <int ACT, int BF16OUT, int VSPLIT>
__global__ __launch_bounds__(256, 2) void gemm_bf16_kernel(
    const u16* __restrict__ A, const u16* __restrict__ W,
    const float* __restrict__ bias, const float* __restrict__ res,
    void* __restrict__ Cout, u16* __restrict__ vtout, int N, int K)
{
    __shared__ __align__(16) char smem[65536];
    // layout: buf0: A @ 0, B @ 16384; buf1: A @ 32768, B @ 49152 (bytes)
    float* Cs = (float*)smem;            // epilogue transpose (reuse)

    const int tid = threadIdx.x;
    const int w = tid >> 6;          // wave 0..3
    const int l = tid & 63;
    const int lr = l & 15;
    const int lq = l >> 4;
    const int wm = w >> 1, wn = w & 1;

    // XCD-band swizzle (Mt = 32, Nt = N/128, NB = Nt/8 n-tiles per XCD)
    const int fid = blockIdx.x;
    const int NB = (N >> 7) >> 3;
    const int xcd = fid & 7;
    const int kk = fid >> 3;
    const int nt = xcd * NB + (kk >> 5);
    const int mt = kk & 31;
    const int m0 = mt * 128, n0 = nt * 128;

    const u16* A_blk = A + (size_t)m0 * K;
    const u16* W_blk = W + (size_t)n0 * K;

    size_t aoff[4];
    #pragma unroll
    for (int j = 0; j < 4; j++) {
        const int idx = w * 4 + j;
        const int mtt = idx >> 1, s = idx & 1;
        aoff[j] = (size_t)(mtt * 16 + lr) * K + s * 32 + lq * 8;
    }

    floatx4 acc[4][4] = {};

    // prologue: stage tile 0 into buffer 0
    #pragma unroll
    for (int j = 0; j < 4; j++) {
        const int idx = w * 4 + j;
        async_copy16(A_blk + aoff[j], (short*)smem + idx * 512);
        async_copy16(W_blk + aoff[j], (short*)(smem + 16384) + idx * 512);
    }
    __syncthreads();

    for (int kb = 0; kb < K; kb += 64) {
        const int cur = (kb >> 6) & 1;
        short* Ac = (short*)(smem + cur * 32768);
        short* Bc = (short*)(smem + cur * 32768 + 16384);
        if (kb + 64 < K) {
            short* An = (short*)(smem + (cur ^ 1) * 32768);
            short* Bn = (short*)(smem + (cur ^ 1) * 32768 + 16384);
            #pragma unroll
            for (int j = 0; j < 4; j++) {
                const int idx = w * 4 + j;
                async_copy16(A_blk + aoff[j] + kb + 64, An + idx * 512);
                async_copy16(W_blk + aoff[j] + kb + 64, Bn + idx * 512);
            }
        }

        #pragma unroll
        for (int s = 0; s < 2; s++) {
            short8 af[4], bfr[4];
            #pragma unroll
            for (int i = 0; i < 4; i++)
                af[i] = *(const short8*)&Ac[(((4 * wm + i) * 2 + s) * 64 + l) * 8];
            #pragma unroll
            for (int j = 0; j < 4; j++)
                bfr[j] = *(const short8*)&Bc[(((4 * wn + j) * 2 + s) * 64 + l) * 8];
            #pragma unroll
            for (int i = 0; i < 4; i++)
                #pragma unroll
                for (int j = 0; j < 4; j++)
                    acc[i][j] = __builtin_amdgcn_mfma_f32_16x16x32_bf16(
                        af[i], bfr[j], acc[i][j], 0, 0, 0);
        }
        __syncthreads();   // drains next-tile copies (hidden behind compute) + LDS reads
    }

    if (VSPLIT && n0 >= 2048) {
        // V-part of QKV: write transposed Vt[((b*16+h)*64+d)*1024 + spos]
        float bj[4];
        #pragma unroll
        for (int j = 0; j < 4; j++) bj[j] = bias[n0 + wn * 64 + j * 16 + lr];
        #pragma unroll
        for (int i = 0; i < 4; i++)
            #pragma unroll
            for (int r = 0; r < 4; r++) {
                const int row = m0 + wm * 64 + i * 16 + lq * 4 + r;  // b*1024+spos
                const int bidx = row >> 10, spos = row & 1023;
                #pragma unroll
                for (int j = 0; j < 4; j++) {
                    const int vcol = (n0 - 2048) + wn * 64 + j * 16 + lr; // h*64+d
                    const float v = acc[i][j][r] + bj[j];
                    vtout[((size_t)(bidx * 16 + (vcol >> 6)) * 64 + (vcol & 63)) * 1024 + spos]
                        = f2bf(v);
                }
            }
        return;
    }

    // epilogue: per m-chunk i, transpose via LDS (stride 136 floats) -> float4 rows
    #pragma unroll
    for (int i = 0; i < 4; i++) {
        __syncthreads();
        #pragma unroll
        for (int r = 0; r < 4; r++) {
            const int rl = wm * 16 + lq * 4 + r;
            #pragma unroll
            for (int j = 0; j < 4; j++)
                Cs[rl * 136 + wn * 64 + j * 16 + lr] = acc[i][j][r];
        }
        __syncthreads();
        const int rid = tid >> 3;                 // 0..31
        const int rr = m0 + (rid >> 4) * 64 + i * 16 + (rid & 15);
        const size_t rowoff = (size_t)rr * N;
        #pragma unroll
        for (int it = 0; it < 4; it++) {
            const int col = ((tid & 7) + it * 8) * 4;   // 0..124
            float4 v = *(const float4*)&Cs[rid * 136 + col];
            const float4 b4 = *(const float4*)&bias[n0 + col];
            v.x += b4.x; v.y += b4.y; v.z += b4.z; v.w += b4.w;
            if (ACT) { v.x = gelu_f(v.x); v.y = gelu_f(v.y); v.z = gelu_f(v.z); v.w = gelu_f(v.w); }
            if (res) {
                const float4 r4 = *(const float4*)&res[rowoff + n0 + col];
                v.x += r4.x; v.y += r4.y; v.z += r4.z; v.w += r4.w;
            }
            if (BF16OUT)
                *(ushort4*)((u16*)Cout + rowoff + n0 + col) =
                    make_ushort4(f2bf(v.x), f2bf(v.y), f2bf(v.z), f2bf(v.w));
            else
                *(float4*)((float*)Cout + rowoff + n0 + col) = v;
        }
    }
}

// ---------------- MFMA flash attention, bf16 in, causal, softcap 6*tanh(s/6) ----------
// grid (64 bh, 16 qt): all qt-blocks of one head share an XCD (linear%8 = bh%8)
// so K/V live in that XCD's L2. qt descending in y so longest blocks launch first.
__global__ __launch_bounds__(256, 4) void attn_mfma_kernel(
    const u16* __restrict__ qkv,   // [4096][3072] bf16 (Q: h*64+d, K: 1024+h*64+d)
    const u16* __restrict__ vt,    // [b][h][64][1024] bf16
    u16* __restrict__ o)           // [4096][1024] bf16
{
    __shared__ __align__(16) short Ks[4096];     // 8 KB
    __shared__ __align__(16) short Vs[4096];     // 8 KB
    __shared__ __align__(16) short Ps[4][1152];  // per-wave 16 x 72 (pad)

    const int qt = 15 - blockIdx.y;
    const int bh = blockIdx.x;
    const int b = bh >> 4, h = bh & 15;
    const int tid = threadIdx.x;
    const int w = tid >> 6, l = tid & 63;
    const int C = l & 15, Qd = l >> 4;

    short8 qf[2];
    {
        const u16* qp = qkv + (size_t)(b * 1024 + qt * 64 + w * 16 + C) * 3072 + h * 64 + Qd * 8;
        qf[0] = *(const short8*)qp;
        qf[1] = *(const short8*)(qp + 32);
    }

    const u16* kbase = qkv + (size_t)(b * 1024) * 3072 + 1024 + h * 64;
    const u16* vbase = vt + (size_t)(b * 16 + h) * 65536;

    float m_i = -1e30f, l_i = 0.f;
    floatx4 oacc[4] = {};

    for (int kt = 0; kt <= qt; kt++) {
        __syncthreads();
        #pragma unroll
        for (int ii = 0; ii < 4; ii++) {
            const int i = w * 4 + ii;
            if (i < 8) {
                const int mt = i >> 1, s = i & 1;
                async_copy16(kbase + (size_t)(kt * 64 + mt * 16 + C) * 3072 + s * 32 + Qd * 8,
                             &Ks[i * 512]);
            } else {
                const int j = i - 8, dt = j >> 1, s = j & 1;
                async_copy16(vbase + (size_t)(dt * 16 + C) * 1024 + kt * 64 + s * 32 + Qd * 8,
                             &Vs[j * 512]);
            }
        }
        __syncthreads();

        floatx4 sacc[4] = {};
        #pragma unroll
        for (int mt = 0; mt < 4; mt++)
            #pragma unroll
            for (int s = 0; s < 2; s++) {
                const short8 kf = *(const short8*)&Ks[((mt * 2 + s) * 64 + l) * 8];
                sacc[mt] = __builtin_amdgcn_mfma_f32_16x16x32_bf16(kf, qf[s], sacc[mt], 0, 0, 0);
            }

        float p[16];
        float tmax = -1e30f;
        const bool diag = (kt == qt);
        const int qrow = qt * 64 + w * 16 + C;
        #pragma unroll
        for (int mt = 0; mt < 4; mt++)
            #pragma unroll
            for (int r = 0; r < 4; r++) {
                const float sv = sacc[mt][r] * 0.125f;
                const float e = __expf(sv * (1.0f / 3.0f));
                float sc = 6.0f - 12.0f / (e + 1.0f);
                if (diag) {
                    const int krow = kt * 64 + mt * 16 + Qd * 4 + r;
                    if (krow > qrow) sc = -1e30f;
                }
                p[mt * 4 + r] = sc;
                tmax = fmaxf(tmax, sc);
            }
        tmax = fmaxf(tmax, __shfl_xor(tmax, 16));
        tmax = fmaxf(tmax, __shfl_xor(tmax, 32));
        const float mnew = fmaxf(m_i, tmax);
        const float alpha = __expf(m_i - mnew);
        float rs = 0.f;
        #pragma unroll
        for (int i = 0; i < 16; i++) { p[i] = __expf(p[i] - mnew); rs += p[i]; }
        rs += __shfl_xor(rs, 16);
        rs += __shfl_xor(rs, 32);
        l_i = l_i * alpha + rs;
        m_i = mnew;

        float av[4];
        #pragma unroll
        for (int r = 0; r < 4; r++) av[r] = __shfl(alpha, Qd * 4 + r);
        #pragma unroll
        for (int dt = 0; dt < 4; dt++)
            #pragma unroll
            for (int r = 0; r < 4; r++) oacc[dt][r] *= av[r];

        #pragma unroll
        for (int mt = 0; mt < 4; mt++)
            #pragma unroll
            for (int pr = 0; pr < 2; pr++) {
                const unsigned int pk =
                    (unsigned)f2bf(p[mt * 4 + pr * 2]) |
                    ((unsigned)f2bf(p[mt * 4 + pr * 2 + 1]) << 16);
                *(unsigned int*)&Ps[w][C * 72 + mt * 16 + Qd * 4 + pr * 2] = pk;
            }
        short8 pf[2];
        pf[0] = *(const short8*)&Ps[w][C * 72 + Qd * 8];
        pf[1] = *(const short8*)&Ps[w][C * 72 + 32 + Qd * 8];

        #pragma unroll
        for (int dt = 0; dt < 4; dt++)
            #pragma unroll
            for (int s = 0; s < 2; s++) {
                const short8 vf = *(const short8*)&Vs[((dt * 2 + s) * 64 + l) * 8];
                oacc[dt] = __builtin_amdgcn_mfma_f32_16x16x32_bf16(pf[s], vf, oacc[dt], 0, 0, 0);
            }
    }

    float linv[4];
    #pragma unroll
    for (int r = 0; r < 4; r++) linv[r] = 1.0f / __shfl(l_i, Qd * 4 + r);
    #pragma unroll
    for (int dt = 0; dt < 4; dt++)
        #pragma unroll
        for (int r = 0; r < 4; r++) {
            const size_t row = (size_t)(b * 1024 + qt * 64 + w * 16 + Qd * 4 + r);
            o[row * 1024 + h * 64 + dt * 16 + C] = f2bf(oacc[dt][r] * linv[r]);
        }
}

extern "C" void kernel_launch(void* const* d_in, const int* in_sizes, int n_in,
                              void* d_out, int out_size, void* d_ws, size_t ws_size,
                              hipStream_t stream)
{
    (void)in_sizes; (void)n_in; (void)out_size; (void)ws_size;
    const float* x     = (const float*)d_in[0];
    // d_in[1] = mask: deterministic causal tril — hardcoded in attn kernel
    const float* qkv_w = (const float*)d_in[2];
    const float* qkv_b = (const float*)d_in[3];
    const float* out_w = (const float*)d_in[4];
    const float* out_b = (const float*)d_in[5];
    const float* ln1_g = (const float*)d_in[6];
    const float* ln1_b = (const float*)d_in[7];
    const float* ln2_g = (const float*)d_in[8];
    const float* ln2_b = (const float*)d_in[9];
    const float* ff1_w = (const float*)d_in[10];
    const float* ff1_b = (const float*)d_in[11];
    const float* ff2_w = (const float*)d_in[12];
    const float* ff2_b = (const float*)d_in[13];
    float* out = (float*)d_out;

    u16* qkvbuf = (u16*)d_ws;
    u16* vtbuf  = (u16*)((char*)d_ws + 25165824);
    u16* hbuf   = (u16*)((char*)d_ws + 33554432);
    u16* obuf   = (u16*)((char*)d_ws + 41943040);
    u16* wq     = (u16*)((char*)d_ws + 50331648);
    u16* wo = wq + 3145728;
    u16* w1 = wo + 1048576;
    u16* w2 = w1 + 2097152;
    u16* ff1buf = qkvbuf;   // qkv dead after attention

    // all 4 weight casts in one launch
    castw4_kernel<<<8192, 256, 0, stream>>>(qkv_w, out_w, ff1_w, ff2_w, wq, wo, w1, w2);

    // 1) h = LN1(x)
    ln_kernel<<<NROWS, 256, 0, stream>>>(x, ln1_g, ln1_b, hbuf);
    // 2) qkv = h @ qkv_w^T + qkv_b  [bf16; V part written transposed to Vt]
    gemm_bf16_kernel<0,1,1><<<768, 256, 0, stream>>>(
        hbuf, wq, qkv_b, nullptr, qkvbuf, vtbuf, 3072, 1024);
    // 3) o = attention(q, k, Vt)
    attn_mfma_kernel<<<dim3(64, 16), 256, 0, stream>>>(qkvbuf, vtbuf, obuf);
    // 4) out = x + o @ out_w^T + out_b  [fp32]
    gemm_bf16_kernel<0,0,0><<<256, 256, 0, stream>>>(
        obuf, wo, out_b, x, out, nullptr, 1024, 1024);
    // 5) h = LN2(out)
    ln_kernel<<<NROWS, 256, 0, stream>>>(out, ln2_g, ln2_b, hbuf);
    // 6) ff1 = gelu(h @ ff1_w^T + ff1_b)  [bf16]
    gemm_bf16_kernel<1,1,0><<<512, 256, 0, stream>>>(
        hbuf, w1, ff1_b, nullptr, ff1buf, nullptr, 2048, 1024);
    // 7) out = out + ff1 @ ff2_w^T + ff2_b  [fp32]
    gemm_bf16_kernel<0,0,0><<<256, 256, 0, stream>>>(
        ff1buf, w2, ff2_b, out, out, nullptr, 1024, 2048);
}